// Round 1
// baseline (2659.045 us; speedup 1.0000x reference)
//
#include <hip/hip_runtime.h>
#include <cstddef>

#define NS 64
#define NC 32
#define NN 96
#define TT 50
#define BB 256

// LDS strides (floats)
#define VS 68    // V rows, 16B-aligned rows, odd bank offset groups
#define FS 100   // F/M rows, 16B-aligned
#define QS 96    // Q rows (exact, so flat float4 staging works)
#define AS 100   // aug rows

// LDS float offsets
#define OFF_V    0          // 64*68   = 4352
#define OFF_Q    4352       // 96*96   = 9216
#define OFF_F    13568      // 64*100  = 6400
#define OFF_M    19968      // 64*100  = 6400
#define OFF_AUG  26368      // 32*100  = 3200
#define OFF_XUT  29568      // 96
#define OFF_CV   29664      // 96
#define OFF_QT   29760      // 96
#define OFF_VV   29856      // 64
#define OFF_CX   29920      // 96
#define LDS_FLOATS 30016    // 120064 bytes

extern "C" __global__ __launch_bounds__(256, 1)
void lqr_bwd(const float* __restrict__ Cg, const float* __restrict__ cg,
             const float* __restrict__ Fg, const float* __restrict__ cxg,
             const float* __restrict__ cug, float* __restrict__ Kg,
             float* __restrict__ kg)
{
    extern __shared__ float sm[];
    float* Vb  = sm + OFF_V;
    float* Qb  = sm + OFF_Q;
    float* Fb  = sm + OFF_F;
    float* Mb  = sm + OFF_M;
    float* Ab  = sm + OFF_AUG;
    float* xut = sm + OFF_XUT;
    float* cv  = sm + OFF_CV;
    float* qtv = sm + OFF_QT;
    float* vv  = sm + OFF_VV;
    float* cxv = sm + OFF_CX;

    const int b   = blockIdx.x;
    const int tid = threadIdx.x;

    // ---- preloop: stage F, xut, cvec for t=49; zero V, v ----
    {
        const int t = TT - 1;
        const float* Fsrc = Fg + ((size_t)t * BB + b) * (NS * NN);
        #pragma unroll
        for (int r = 0; r < 6; ++r) {
            int f = tid + 256 * r;                 // float4 index, < 1536
            float4 val = ((const float4*)Fsrc)[f];
            int row = f / 24, c4 = f % 24;
            *(float4*)&Fb[row * FS + c4 * 4] = val;
        }
        if (tid < NN) {
            xut[tid] = (tid < NS) ? cxg[((size_t)t * BB + b) * NS + tid]
                                  : cug[((size_t)t * BB + b) * NC + (tid - NS)];
            cv[tid] = cg[((size_t)t * BB + b) * NN + tid];
        }
        for (int e = tid; e < NS * VS; e += 256) Vb[e] = 0.f;
        if (tid < NS) vv[tid] = 0.f;
    }
    __syncthreads();

    for (int t = TT - 1; t >= 0; --t) {
        // ---- top: issue staged global loads (C_t now; F/xut/c for t-1) ----
        const float* Csrc = Cg + ((size_t)t * BB + b) * (NN * NN);
        float4 creg[9];
        #pragma unroll
        for (int r = 0; r < 9; ++r) creg[r] = ((const float4*)Csrc)[tid + 256 * r];

        float4 freg[6];
        float xreg = 0.f, cvreg = 0.f;
        if (t > 0) {
            const float* Fsrc = Fg + ((size_t)(t - 1) * BB + b) * (NS * NN);
            #pragma unroll
            for (int r = 0; r < 6; ++r) freg[r] = ((const float4*)Fsrc)[tid + 256 * r];
            if (tid < NN) {
                xreg  = (tid < NS) ? cxg[((size_t)(t - 1) * BB + b) * NS + tid]
                                   : cug[((size_t)(t - 1) * BB + b) * NC + (tid - NS)];
                cvreg = cg[((size_t)(t - 1) * BB + b) * NN + tid];
            }
        }

        // ---- P1: M = V @ F  (tiles 4i x 6j, k-chunks of 4) ----
        {
            const int ty = tid >> 4, tx = tid & 15;
            const int i0 = 4 * ty, j0 = 6 * tx;
            float acc[4][6];
            #pragma unroll
            for (int a = 0; a < 4; ++a)
                #pragma unroll
                for (int q = 0; q < 6; ++q) acc[a][q] = 0.f;
            for (int k = 0; k < NS; k += 4) {
                float4 vr[4];
                #pragma unroll
                for (int di = 0; di < 4; ++di)
                    vr[di] = *(const float4*)&Vb[(i0 + di) * VS + k];
                #pragma unroll
                for (int dk = 0; dk < 4; ++dk) {
                    float2 f0 = *(const float2*)&Fb[(k + dk) * FS + j0];
                    float2 f1 = *(const float2*)&Fb[(k + dk) * FS + j0 + 2];
                    float2 f2 = *(const float2*)&Fb[(k + dk) * FS + j0 + 4];
                    float fv[6] = {f0.x, f0.y, f1.x, f1.y, f2.x, f2.y};
                    #pragma unroll
                    for (int di = 0; di < 4; ++di) {
                        float vk = (&vr[di].x)[dk];
                        #pragma unroll
                        for (int q = 0; q < 6; ++q) acc[di][q] += vk * fv[q];
                    }
                }
            }
            #pragma unroll
            for (int di = 0; di < 4; ++di) {
                *(float2*)&Mb[(i0 + di) * FS + j0]     = make_float2(acc[di][0], acc[di][1]);
                *(float2*)&Mb[(i0 + di) * FS + j0 + 2] = make_float2(acc[di][2], acc[di][3]);
                *(float2*)&Mb[(i0 + di) * FS + j0 + 4] = make_float2(acc[di][4], acc[di][5]);
            }
        }
        // write C regs -> Qb (vmcnt wait lands here, overlapped with P1)
        #pragma unroll
        for (int r = 0; r < 9; ++r) ((float4*)Qb)[tid + 256 * r] = creg[r];
        __syncthreads();   // BAR1

        // ---- P2a: cx = C @ xut  (C symmetric: read column tid => conflict-free) ----
        if (tid < NN) {
            float s0 = 0.f, s1 = 0.f;
            for (int bb2 = 0; bb2 < NN; bb2 += 2) {
                s0 += Qb[bb2 * QS + tid] * xut[bb2];
                s1 += Qb[(bb2 + 1) * QS + tid] * xut[bb2 + 1];
            }
            cxv[tid] = s0 + s1;
        }
        __syncthreads();   // BAR1.5

        // ---- P2b: Q = C + F^T M   (tiles 6a x 6b, in-place over Qb) ----
        {
            const int ty = tid >> 4, tx = tid & 15;
            const int a0 = 6 * ty, b0 = 6 * tx;
            float acc[6][6];
            #pragma unroll
            for (int da = 0; da < 6; ++da) {
                float2 q0 = *(const float2*)&Qb[(a0 + da) * QS + b0];
                float2 q1 = *(const float2*)&Qb[(a0 + da) * QS + b0 + 2];
                float2 q2 = *(const float2*)&Qb[(a0 + da) * QS + b0 + 4];
                acc[da][0] = q0.x; acc[da][1] = q0.y; acc[da][2] = q1.x;
                acc[da][3] = q1.y; acc[da][4] = q2.x; acc[da][5] = q2.y;
            }
            for (int i = 0; i < NS; ++i) {
                float2 fa0 = *(const float2*)&Fb[i * FS + a0];
                float2 fa1 = *(const float2*)&Fb[i * FS + a0 + 2];
                float2 fa2 = *(const float2*)&Fb[i * FS + a0 + 4];
                float2 mb0 = *(const float2*)&Mb[i * FS + b0];
                float2 mb1 = *(const float2*)&Mb[i * FS + b0 + 2];
                float2 mb2 = *(const float2*)&Mb[i * FS + b0 + 4];
                float fa[6] = {fa0.x, fa0.y, fa1.x, fa1.y, fa2.x, fa2.y};
                float mb[6] = {mb0.x, mb0.y, mb1.x, mb1.y, mb2.x, mb2.y};
                #pragma unroll
                for (int da = 0; da < 6; ++da)
                    #pragma unroll
                    for (int db = 0; db < 6; ++db) acc[da][db] += fa[da] * mb[db];
            }
            #pragma unroll
            for (int da = 0; da < 6; ++da) {
                *(float2*)&Qb[(a0 + da) * QS + b0]     = make_float2(acc[da][0], acc[da][1]);
                *(float2*)&Qb[(a0 + da) * QS + b0 + 2] = make_float2(acc[da][2], acc[da][3]);
                *(float2*)&Qb[(a0 + da) * QS + b0 + 4] = make_float2(acc[da][4], acc[da][5]);
            }
        }
        __syncthreads();   // BAR2

        // ---- P3: qt = c + cx + F^T v ; build aug = [Q_uu | Q_ux | q_u] ----
        if (tid < NN) {
            float s0 = cv[tid] + cxv[tid], s1 = 0.f;
            for (int i = 0; i < NS; i += 2) {
                s0 += Fb[i * FS + tid] * vv[i];
                s1 += Fb[(i + 1) * FS + tid] * vv[i + 1];
            }
            float s = s0 + s1;
            qtv[tid] = s;
            if (tid >= NS) Ab[(tid - NS) * AS + 96] = s;   // q_u
        }
        for (int e = tid; e < NC * NN; e += 256) {
            int r = e / NN, j = e % NN;
            float val = (j < NC) ? Qb[(NS + r) * QS + NS + j]
                                 : Qb[(NS + r) * QS + (j - NC)];
            Ab[r * AS + j] = val;
        }
        __syncthreads();   // BAR3

        // ---- staging writes for next step (Fb/xut/cv free now; runs under P4) ----
        if (t > 0) {
            #pragma unroll
            for (int r = 0; r < 6; ++r) {
                int f = tid + 256 * r;
                int row = f / 24, c4 = f % 24;
                *(float4*)&Fb[row * FS + c4 * 4] = freg[r];
            }
            if (tid < NN) { xut[tid] = xreg; cv[tid] = cvreg; }
        }

        // ---- P4: Gauss-Jordan on aug (SPD, no pivoting), deferred row scaling ----
        {
            const int r  = tid >> 3;        // 0..31
            const int jc = tid & 7;         // 0..7
            const int jlo = jc * 13;
            const int jhi = (jlo + 13 < 97) ? (jlo + 13) : 97;
            for (int p = 0; p < NC; ++p) {
                float piv = Ab[p * AS + p];
                float fac = Ab[r * AS + p] / piv;
                if (r != p) {
                    for (int j = jlo; j < jhi; ++j)
                        Ab[r * AS + j] -= fac * Ab[p * AS + j];
                }
                __syncthreads();
            }
            // scale RHS block by -1/d_r  => aug[:,32:97] = [K | kt]
            float inv = 1.f / Ab[r * AS + r];
            for (int j = jlo; j < jhi; ++j)
                if (j >= NC) Ab[r * AS + j] *= -inv;
        }
        __syncthreads();   // BAR4

        // ---- store K, kt to global (coalesced) ----
        {
            float* Kt = Kg + ((size_t)t * BB + b) * (NC * NS);
            for (int e = tid; e < NC * NS; e += 256) {
                int m = e >> 6, x = e & 63;
                Kt[e] = Ab[m * AS + 32 + x];
            }
            if (tid < NC) kg[((size_t)t * BB + b) * NC + tid] = Ab[tid * AS + 96];
        }

        // ---- P5: Vn = Q_xx + Q_xu K (4x4 tiles); vn = q_x + Q_xu kt ----
        {
            const int ty = tid >> 4, tx = tid & 15;
            const int i0 = 4 * ty, j0 = 4 * tx;
            float acc[4][4];
            #pragma unroll
            for (int di = 0; di < 4; ++di) {
                float4 q = *(const float4*)&Qb[(i0 + di) * QS + j0];
                acc[di][0] = q.x; acc[di][1] = q.y; acc[di][2] = q.z; acc[di][3] = q.w;
            }
            for (int m = 0; m < NC; ++m) {
                float4 qx = *(const float4*)&Qb[(NS + m) * QS + i0];  // Q_xu via symmetry
                float4 kk = *(const float4*)&Ab[m * AS + 32 + j0];
                float qv[4] = {qx.x, qx.y, qx.z, qx.w};
                float kv[4] = {kk.x, kk.y, kk.z, kk.w};
                #pragma unroll
                for (int di = 0; di < 4; ++di)
                    #pragma unroll
                    for (int dj = 0; dj < 4; ++dj) acc[di][dj] += qv[di] * kv[dj];
            }
            #pragma unroll
            for (int di = 0; di < 4; ++di)
                *(float4*)&Vb[(i0 + di) * VS + j0] =
                    make_float4(acc[di][0], acc[di][1], acc[di][2], acc[di][3]);
        }
        if (tid < NS) {
            float s0 = qtv[tid], s1 = 0.f;
            for (int m = 0; m < NC; m += 2) {
                s0 += Qb[(NS + m) * QS + tid] * Ab[m * AS + 96];
                s1 += Qb[(NS + m + 1) * QS + tid] * Ab[(m + 1) * AS + 96];
            }
            vv[tid] = s0 + s1;
        }
        __syncthreads();   // BAR5 (end of step)
    }
}

extern "C" __global__ __launch_bounds__(256, 1)
void lqr_fwd(const float* __restrict__ x_init, const float* __restrict__ Fg,
             const float* __restrict__ cxg, const float* __restrict__ cug,
             const float* __restrict__ Kg, const float* __restrict__ kg,
             float* __restrict__ out)
{
    __shared__ float xpp[2][96];   // [0:64)=x carry, [64:96)=u_new
    __shared__ float dxs[2][64];
    const int b = blockIdx.x, tid = threadIdx.x;
    float* out_x = out;                           // T*B*64
    float* out_u = out + (size_t)TT * BB * NS;    // T*B*32

    if (tid < NS) { xpp[0][tid] = x_init[(size_t)b * NS + tid]; dxs[0][tid] = 0.f; }
    __syncthreads();

    const int mK = tid >> 3, qK = tid & 7;   // u-phase: 32 rows x 8 lanes
    const int iF = tid >> 2, qF = tid & 3;   // x-phase: 64 rows x 4 lanes

    float kr[8], fr[24];
    {
        const float* Ksrc = Kg + (size_t)b * (NC * NS);
        #pragma unroll
        for (int xx = 0; xx < 8; ++xx) kr[xx] = Ksrc[mK * NS + qK + 8 * xx];
        const float* Fsrc = Fg + (size_t)b * (NS * NN);
        #pragma unroll
        for (int jj = 0; jj < 24; ++jj) fr[jj] = Fsrc[iF * NN + qF + 4 * jj];
    }

    for (int t = 0; t < TT; ++t) {
        const int cur = t & 1, nxt = cur ^ 1;
        // prefetch t+1 (clamped)
        float krn[8], frn[24];
        {
            int tn = (t + 1 < TT) ? (t + 1) : t;
            const float* Ksrc = Kg + ((size_t)tn * BB + b) * (NC * NS);
            #pragma unroll
            for (int xx = 0; xx < 8; ++xx) krn[xx] = Ksrc[mK * NS + qK + 8 * xx];
            const float* Fsrc = Fg + ((size_t)tn * BB + b) * (NS * NN);
            #pragma unroll
            for (int jj = 0; jj < 24; ++jj) frn[jj] = Fsrc[iF * NN + qF + 4 * jj];
        }
        // new_x[t] = x carry
        if (tid < NS) out_x[((size_t)t * BB + b) * NS + tid] = xpp[cur][tid];
        // u-phase: u_new = K dx + u + k
        {
            float s = 0.f;
            #pragma unroll
            for (int xx = 0; xx < 8; ++xx) s += kr[xx] * dxs[cur][qK + 8 * xx];
            s += __shfl_down(s, 4); s += __shfl_down(s, 2); s += __shfl_down(s, 1);
            if (qK == 0) {
                float un = s + cug[((size_t)t * BB + b) * NC + mK]
                             + kg[((size_t)t * BB + b) * NC + mK];
                xpp[cur][NS + mK] = un;
                out_u[((size_t)t * BB + b) * NC + mK] = un;
            }
        }
        __syncthreads();
        // x-phase: x_next = F @ [x; u_new]
        {
            float s = 0.f;
            #pragma unroll
            for (int jj = 0; jj < 24; ++jj) s += fr[jj] * xpp[cur][qF + 4 * jj];
            s += __shfl_down(s, 2); s += __shfl_down(s, 1);
            if (qF == 0) {
                float xr = (t + 1 < TT) ? cxg[((size_t)(t + 1) * BB + b) * NS + iF] : 0.f;
                xpp[nxt][iF] = s;
                dxs[nxt][iF] = s - xr;
            }
        }
        __syncthreads();
        #pragma unroll
        for (int xx = 0; xx < 8; ++xx) kr[xx] = krn[xx];
        #pragma unroll
        for (int jj = 0; jj < 24; ++jj) fr[jj] = frn[jj];
    }
}

extern "C" void kernel_launch(void* const* d_in, const int* in_sizes, int n_in,
                              void* d_out, int out_size, void* d_ws, size_t ws_size,
                              hipStream_t stream)
{
    const float* x_init = (const float*)d_in[0];
    const float* Cg     = (const float*)d_in[1];
    const float* cg     = (const float*)d_in[2];
    const float* Fg     = (const float*)d_in[3];
    const float* cxg    = (const float*)d_in[4];
    const float* cug    = (const float*)d_in[5];
    float* out = (float*)d_out;

    float* Kg = (float*)d_ws;                              // T*B*32*64 floats
    float* kg = Kg + (size_t)TT * BB * NC * NS;            // T*B*32 floats

    hipFuncSetAttribute((const void*)lqr_bwd,
                        hipFuncAttributeMaxDynamicSharedMemorySize,
                        LDS_FLOATS * 4);

    lqr_bwd<<<BB, 256, LDS_FLOATS * 4, stream>>>(Cg, cg, Fg, cxg, cug, Kg, kg);
    lqr_fwd<<<BB, 256, 0, stream>>>(x_init, Fg, cxg, cug, Kg, kg, out);
}

// Round 2
// 1879.351 us; speedup vs baseline: 1.4149x; 1.4149x over previous
//
#include <hip/hip_runtime.h>
#include <cstddef>

#define NS 64
#define NC 32
#define NN 96
#define TT 50
#define BB 256
#define NT 512   // threads per block (8 waves)

// LDS strides (floats). 104 % 32 == 8 -> adjacent padded rows land 8 banks
// apart, killing the stride-96 (==0 mod 32) 4-way conflicts of round 1.
#define VS 68
#define QS 104
#define FS 104
#define AS 104

// LDS float offsets
#define OFF_V    0          // 64*68  = 4352
#define OFF_Q    4352       // 96*104 = 9984
#define OFF_F    14336      // 64*104 = 6656
#define OFF_M    20992      // 64*104 = 6656
#define OFF_A    27648      // 32*104 = 3328
#define OFF_PROW 30976      // 2*104
#define OFF_PCOL 31184      // 2*32
#define OFF_XUT  31248      // 96
#define OFF_CV   31344      // 96
#define OFF_QT   31440      // 96
#define OFF_VV   31536      // 64
#define LDS_FLOATS 31600    // 126400 bytes -> 1 block/CU (fine: grid==CUs)

extern "C" __global__ __launch_bounds__(NT, 1)
void lqr_fused(const float* __restrict__ x_init,
               const float* __restrict__ Cg, const float* __restrict__ cg,
               const float* __restrict__ Fg, const float* __restrict__ cxg,
               const float* __restrict__ cug, float* __restrict__ Kg,
               float* __restrict__ kg, float* __restrict__ out)
{
    extern __shared__ float sm[];
    float* Vb   = sm + OFF_V;
    float* Qb   = sm + OFF_Q;
    float* Fb   = sm + OFF_F;
    float* Mb   = sm + OFF_M;
    float* Ab   = sm + OFF_A;
    float* prow = sm + OFF_PROW;   // [2][104]
    float* pcol = sm + OFF_PCOL;   // [2][32]
    float* xut  = sm + OFF_XUT;
    float* cv   = sm + OFF_CV;
    float* qtv  = sm + OFF_QT;
    float* vv   = sm + OFF_VV;

    const int b   = blockIdx.x;
    const int tid = threadIdx.x;

    float4 creg[5];   // C_t, pipelined one full t-step ahead
    float4 fnew[3];
    float  xreg = 0.f, cvreg = 0.f;

    // ================= preloop: stage F/xut/c for t=49; load C(49); zero V,v =====
    {
        const int t = TT - 1;
        const float* Fsrc = Fg + ((size_t)t * BB + b) * (NS * NN);
        #pragma unroll
        for (int rr = 0; rr < 3; ++rr) {
            int f = tid + NT * rr;                 // < 1536
            float4 val = ((const float4*)Fsrc)[f];
            int row = f / 24, c4 = f % 24;
            *(float4*)&Fb[row * FS + 4 * c4] = val;
        }
        const float* Csrc = Cg + ((size_t)t * BB + b) * (NN * NN);
        #pragma unroll
        for (int rr = 0; rr < 4; ++rr) creg[rr] = ((const float4*)Csrc)[tid + NT * rr];
        if (tid < 256) creg[4] = ((const float4*)Csrc)[tid + 2048];

        if (tid < NN) {
            xut[tid] = (tid < NS) ? cxg[((size_t)t * BB + b) * NS + tid]
                                  : cug[((size_t)t * BB + b) * NC + (tid - NS)];
            cv[tid] = cg[((size_t)t * BB + b) * NN + tid];
        }
        for (int e = tid; e < NS * VS; e += NT) Vb[e] = 0.f;
        if (tid < NS) vv[tid] = 0.f;
    }
    __syncthreads();

    // ================= backward Riccati scan =================
    for (int t = TT - 1; t >= 0; --t) {
        // ---- A: write pipelined C regs -> Qb (loaded a full step ago: no vmcnt stall)
        #pragma unroll
        for (int rr = 0; rr < 5; ++rr) {
            if (rr < 4 || tid < 256) {
                int f = tid + NT * rr;
                int row = f / 24, c4 = f % 24;
                *(float4*)&Qb[row * QS + 4 * c4] = creg[rr];
            }
        }
        // ---- B: issue global loads for t-1 (land during GJ etc.)
        if (t > 0) {
            const float* Cs = Cg + ((size_t)(t - 1) * BB + b) * (NN * NN);
            #pragma unroll
            for (int rr = 0; rr < 4; ++rr) creg[rr] = ((const float4*)Cs)[tid + NT * rr];
            if (tid < 256) creg[4] = ((const float4*)Cs)[tid + 2048];
            const float* Fs = Fg + ((size_t)(t - 1) * BB + b) * (NS * NN);
            #pragma unroll
            for (int rr = 0; rr < 3; ++rr) fnew[rr] = ((const float4*)Fs)[tid + NT * rr];
            if (tid < NN) {
                xreg  = (tid < NS) ? cxg[((size_t)(t - 1) * BB + b) * NS + tid]
                                   : cug[((size_t)(t - 1) * BB + b) * NC + (tid - NS)];
                cvreg = cg[((size_t)(t - 1) * BB + b) * NN + tid];
            }
        }

        // ---- P1: M = V @ F  (tile 2 rows x 6 cols; V/F reads broadcast across lanes)
        {
            const int ty = tid >> 4, tx = tid & 15;
            const int i0 = 2 * ty, j0 = 6 * tx;
            float acc[2][6];
            #pragma unroll
            for (int a = 0; a < 2; ++a)
                #pragma unroll
                for (int q = 0; q < 6; ++q) acc[a][q] = 0.f;
            for (int k = 0; k < NS; k += 4) {
                float4 v0 = *(const float4*)&Vb[i0 * VS + k];
                float4 v1 = *(const float4*)&Vb[(i0 + 1) * VS + k];
                #pragma unroll
                for (int dk = 0; dk < 4; ++dk) {
                    float2 f0 = *(const float2*)&Fb[(k + dk) * FS + j0];
                    float2 f1 = *(const float2*)&Fb[(k + dk) * FS + j0 + 2];
                    float2 f2 = *(const float2*)&Fb[(k + dk) * FS + j0 + 4];
                    float fv[6] = {f0.x, f0.y, f1.x, f1.y, f2.x, f2.y};
                    float a0k = (&v0.x)[dk], a1k = (&v1.x)[dk];
                    #pragma unroll
                    for (int q = 0; q < 6; ++q) {
                        acc[0][q] += a0k * fv[q];
                        acc[1][q] += a1k * fv[q];
                    }
                }
            }
            #pragma unroll
            for (int a = 0; a < 2; ++a) {
                *(float2*)&Mb[(i0 + a) * FS + j0]     = make_float2(acc[a][0], acc[a][1]);
                *(float2*)&Mb[(i0 + a) * FS + j0 + 2] = make_float2(acc[a][2], acc[a][3]);
                *(float2*)&Mb[(i0 + a) * FS + j0 + 4] = make_float2(acc[a][4], acc[a][5]);
            }
        }
        __syncthreads();   // BAR1: C in Qb, M ready

        // ---- P2a: qt = c + C^T xut + F^T v  (C symmetric; column reads 2-way = free)
        if (tid < NN) {
            const int j = tid;
            float s0 = cv[j], s1 = 0.f;
            for (int i = 0; i < NN; i += 2) {
                s0 += Qb[i * QS + j] * xut[i];
                s1 += Qb[(i + 1) * QS + j] * xut[i + 1];
            }
            for (int i = 0; i < NS; i += 2) {
                s0 += Fb[i * FS + j] * vv[i];
                s1 += Fb[(i + 1) * FS + j] * vv[i + 1];
            }
            float s = s0 + s1;
            qtv[j] = s;
            if (j >= NS) Ab[(j - NS) * AS + 96] = s;   // q_u
        }
        __syncthreads();   // BAR1.5: all C reads done before in-place overwrite

        // ---- P2b: Q = C + F^T M (in place), dual-write ctrl rows into aug ----
        {
            const int ty = tid >> 4, tx = tid & 15;
            const int a0 = 3 * ty, b0 = 6 * tx;     // 3 rows x 6 cols
            float acc[3][6];
            #pragma unroll
            for (int dr = 0; dr < 3; ++dr) {
                float2 q0 = *(const float2*)&Qb[(a0 + dr) * QS + b0];
                float2 q1 = *(const float2*)&Qb[(a0 + dr) * QS + b0 + 2];
                float2 q2 = *(const float2*)&Qb[(a0 + dr) * QS + b0 + 4];
                acc[dr][0] = q0.x; acc[dr][1] = q0.y; acc[dr][2] = q1.x;
                acc[dr][3] = q1.y; acc[dr][4] = q2.x; acc[dr][5] = q2.y;
            }
            for (int i = 0; i < NS; ++i) {
                float fa0 = Fb[i * FS + a0];
                float fa1 = Fb[i * FS + a0 + 1];
                float fa2 = Fb[i * FS + a0 + 2];
                float2 m0 = *(const float2*)&Mb[i * FS + b0];
                float2 m1 = *(const float2*)&Mb[i * FS + b0 + 2];
                float2 m2 = *(const float2*)&Mb[i * FS + b0 + 4];
                float mb[6] = {m0.x, m0.y, m1.x, m1.y, m2.x, m2.y};
                float fa[3] = {fa0, fa1, fa2};
                #pragma unroll
                for (int dr = 0; dr < 3; ++dr)
                    #pragma unroll
                    for (int q = 0; q < 6; ++q) acc[dr][q] += fa[dr] * mb[q];
            }
            #pragma unroll
            for (int dr = 0; dr < 3; ++dr) {
                *(float2*)&Qb[(a0 + dr) * QS + b0]     = make_float2(acc[dr][0], acc[dr][1]);
                *(float2*)&Qb[(a0 + dr) * QS + b0 + 2] = make_float2(acc[dr][2], acc[dr][3]);
                *(float2*)&Qb[(a0 + dr) * QS + b0 + 4] = make_float2(acc[dr][4], acc[dr][5]);
                int row = a0 + dr;
                if (row >= NS) {                        // aug row: [Q_uu | Q_ux]
                    int rr = row - NS;
                    #pragma unroll
                    for (int q = 0; q < 6; ++q) {
                        int c  = b0 + q;
                        int ac = (c < NS) ? (c + NC) : (c - NS);
                        Ab[rr * AS + ac] = acc[dr][q];
                    }
                }
            }
        }
        __syncthreads();   // BAR2: Q and aug ready; Fb free

        // ---- stage F/xut/c for t-1 (overlaps GJ region) ----
        if (t > 0) {
            #pragma unroll
            for (int rr = 0; rr < 3; ++rr) {
                int f = tid + NT * rr;
                int row = f / 24, c4 = f % 24;
                *(float4*)&Fb[row * FS + 4 * c4] = fnew[rr];
            }
            if (tid < NN) { xut[tid] = xreg; cv[tid] = cvreg; }
        }

        // ---- GJ: register-resident rows; publish only next pivot row/col ----
        float myinv;
        {
            const int g = tid & 15, r = tid >> 4;   // r 0..31, g 0..15
            const int jlo = 6 * g;
            float a[6], a6;
            #pragma unroll
            for (int q = 0; q < 6; ++q) a[q] = Ab[r * AS + jlo + q];
            a6 = (g == 15) ? Ab[r * AS + 96] : 0.f;
            myinv = 0.f;
            if (r == 0) {
                #pragma unroll
                for (int q = 0; q < 6; ++q) prow[jlo + q] = a[q];
                if (g == 15) prow[96] = a6;
            }
            if (g == 0) pcol[r] = a[0];
            __syncthreads();   // GJ init barrier

            #pragma unroll
            for (int p = 0; p < NC; ++p) {
                const int buf = (p & 1) * 104, nb = ((p + 1) & 1) * 104;
                const int cbuf = (p & 1) * 32, cnb = ((p + 1) & 1) * 32;
                float piv = prow[buf + p];
                float pc  = pcol[cbuf + r];
                float r0  = __builtin_amdgcn_rcpf(piv);
                r0 = r0 * (2.f - piv * r0);          // 1 Newton step ~ IEEE rcp
                float fac = (r == p) ? 0.f : pc * r0;
                float2 w0 = *(const float2*)&prow[buf + jlo];
                float2 w1 = *(const float2*)&prow[buf + jlo + 2];
                float2 w2 = *(const float2*)&prow[buf + jlo + 4];
                float w6  = prow[buf + 96];
                a[0] -= fac * w0.x; a[1] -= fac * w0.y;
                a[2] -= fac * w1.x; a[3] -= fac * w1.y;
                a[4] -= fac * w2.x; a[5] -= fac * w2.y;
                a6   -= fac * w6;
                myinv = (r == p) ? r0 : myinv;
                if (p < NC - 1) {
                    const int np = p + 1;
                    if (g == np / 6) pcol[cnb + r] = a[np % 6];
                    if (r == np) {
                        *(float2*)&prow[nb + jlo]     = make_float2(a[0], a[1]);
                        *(float2*)&prow[nb + jlo + 2] = make_float2(a[2], a[3]);
                        *(float2*)&prow[nb + jlo + 4] = make_float2(a[4], a[5]);
                        if (g == 15) prow[nb + 96] = a6;
                    }
                }
                __syncthreads();
            }
            // write back scaled RHS: aug[:,32:97] = [K | kt]
            #pragma unroll
            for (int q = 0; q < 6; ++q) {
                int j = jlo + q;
                if (j >= NC) Ab[r * AS + j] = -a[q] * myinv;
            }
            if (g == 15) Ab[r * AS + 96] = -a6 * myinv;
        }
        __syncthreads();   // BAR4: K,kt in Ab

        // ---- store K,kt; P5: Vn = Q_xx + Q_xu K; vn ----
        {
            float* Kt = Kg + ((size_t)t * BB + b) * (NC * NS);
            for (int e = tid; e < NC * NS; e += NT) {
                int m = e >> 6, x = e & 63;
                Kt[e] = Ab[m * AS + 32 + x];
            }
            if (tid < NC) kg[((size_t)t * BB + b) * NC + tid] = Ab[tid * AS + 96];
        }
        {
            const int ty = tid >> 4, tx = tid & 15;
            const int i0 = 2 * ty, j0 = 4 * tx;     // 2 rows x 4 cols
            float acc[2][4];
            #pragma unroll
            for (int di = 0; di < 2; ++di) {
                float4 q = *(const float4*)&Qb[(i0 + di) * QS + j0];
                acc[di][0] = q.x; acc[di][1] = q.y; acc[di][2] = q.z; acc[di][3] = q.w;
            }
            for (int m = 0; m < NC; ++m) {
                float2 qx = *(const float2*)&Qb[(NS + m) * QS + i0];  // Q_xu via symmetry
                float4 kk = *(const float4*)&Ab[m * AS + 32 + j0];
                float kv[4] = {kk.x, kk.y, kk.z, kk.w};
                #pragma unroll
                for (int dj = 0; dj < 4; ++dj) {
                    acc[0][dj] += qx.x * kv[dj];
                    acc[1][dj] += qx.y * kv[dj];
                }
            }
            #pragma unroll
            for (int di = 0; di < 2; ++di)
                *(float4*)&Vb[(i0 + di) * VS + j0] =
                    make_float4(acc[di][0], acc[di][1], acc[di][2], acc[di][3]);
        }
        if (tid < NS) {
            float s0 = qtv[tid], s1 = 0.f;
            for (int m = 0; m < NC; m += 2) {
                s0 += Qb[(NS + m) * QS + tid] * Ab[m * AS + 96];
                s1 += Qb[(NS + m + 1) * QS + tid] * Ab[(m + 1) * AS + 96];
            }
            vv[tid] = s0 + s1;
        }
        __syncthreads();   // BAR5: end of t-step
    }

    // ================= fused forward rollout (tid<256 compute; all hit barriers) ===
    {
        float* xpp = sm;          // [2][96]
        float* dxs = sm + 192;    // [2][64]
        float* out_x = out;                            // T*B*64
        float* out_u = out + (size_t)TT * BB * NS;     // T*B*32

        if (tid < NS) { xpp[tid] = x_init[(size_t)b * NS + tid]; dxs[tid] = 0.f; }
        __syncthreads();

        const int mK = tid >> 3, qK = tid & 7;   // u-phase: 32 rows x 8 lanes
        const int iF = tid >> 2, qF = tid & 3;   // x-phase: 64 rows x 4 lanes
        float kr[8], fr[24];
        if (tid < 256) {
            const float* Ksrc = Kg + (size_t)b * (NC * NS);
            #pragma unroll
            for (int xx = 0; xx < 8; ++xx) kr[xx] = Ksrc[mK * NS + qK + 8 * xx];
            const float* Fsrc = Fg + (size_t)b * (NS * NN);
            #pragma unroll
            for (int jj = 0; jj < 24; ++jj) fr[jj] = Fsrc[iF * NN + qF + 4 * jj];
        }

        for (int t = 0; t < TT; ++t) {
            const int cur = (t & 1) * 96, nxt = ((t + 1) & 1) * 96;
            const int curd = (t & 1) * 64, nxtd = ((t + 1) & 1) * 64;
            float krn[8], frn[24];
            if (tid < 256) {
                int tn = (t + 1 < TT) ? (t + 1) : t;
                const float* Ksrc = Kg + ((size_t)tn * BB + b) * (NC * NS);
                #pragma unroll
                for (int xx = 0; xx < 8; ++xx) krn[xx] = Ksrc[mK * NS + qK + 8 * xx];
                const float* Fsrc = Fg + ((size_t)tn * BB + b) * (NS * NN);
                #pragma unroll
                for (int jj = 0; jj < 24; ++jj) frn[jj] = Fsrc[iF * NN + qF + 4 * jj];
            }
            if (tid < NS) out_x[((size_t)t * BB + b) * NS + tid] = xpp[cur + tid];
            if (tid < 256) {
                float s = 0.f;
                #pragma unroll
                for (int xx = 0; xx < 8; ++xx) s += kr[xx] * dxs[curd + qK + 8 * xx];
                s += __shfl_down(s, 4); s += __shfl_down(s, 2); s += __shfl_down(s, 1);
                if (qK == 0) {
                    float un = s + cug[((size_t)t * BB + b) * NC + mK]
                                 + kg[((size_t)t * BB + b) * NC + mK];
                    xpp[cur + NS + mK] = un;
                    out_u[((size_t)t * BB + b) * NC + mK] = un;
                }
            }
            __syncthreads();
            if (tid < 256) {
                float s = 0.f;
                #pragma unroll
                for (int jj = 0; jj < 24; ++jj) s += fr[jj] * xpp[cur + qF + 4 * jj];
                s += __shfl_down(s, 2); s += __shfl_down(s, 1);
                if (qF == 0) {
                    float xr = (t + 1 < TT) ? cxg[((size_t)(t + 1) * BB + b) * NS + iF] : 0.f;
                    xpp[nxt + iF] = s;
                    dxs[nxtd + iF] = s - xr;
                }
                #pragma unroll
                for (int xx = 0; xx < 8; ++xx) kr[xx] = krn[xx];
                #pragma unroll
                for (int jj = 0; jj < 24; ++jj) fr[jj] = frn[jj];
            }
            __syncthreads();
        }
    }
}

extern "C" void kernel_launch(void* const* d_in, const int* in_sizes, int n_in,
                              void* d_out, int out_size, void* d_ws, size_t ws_size,
                              hipStream_t stream)
{
    const float* x_init = (const float*)d_in[0];
    const float* Cg     = (const float*)d_in[1];
    const float* cg     = (const float*)d_in[2];
    const float* Fg     = (const float*)d_in[3];
    const float* cxg    = (const float*)d_in[4];
    const float* cug    = (const float*)d_in[5];
    float* out = (float*)d_out;

    float* Kg = (float*)d_ws;                              // T*B*32*64 floats
    float* kg = Kg + (size_t)TT * BB * NC * NS;            // T*B*32 floats

    hipFuncSetAttribute((const void*)lqr_fused,
                        hipFuncAttributeMaxDynamicSharedMemorySize,
                        LDS_FLOATS * 4);

    lqr_fused<<<BB, NT, LDS_FLOATS * 4, stream>>>(x_init, Cg, cg, Fg, cxg, cug,
                                                  Kg, kg, out);
}